// Round 1
// baseline (1387.510 us; speedup 1.0000x reference)
//
#include <hip/hip_runtime.h>
#include <math.h>

namespace {

constexpr int kB  = 4;
constexpr int kH  = 90;
constexpr int kW  = 180;
constexpr int kC  = 768;
constexpr int kNB = 8;
constexpr int kBS = 96;
constexpr int kM  = 46;          // kept W modes (c1)
constexpr float kLam = 0.01f;    // softshrink lambda
constexpr float kInv180 = 0.07453559924999299f;  // 1/sqrt(180)
constexpr float kInv90  = 0.10540925533894598f;  // 1/sqrt(90)
constexpr float kTwoPi  = 6.283185307179586f;

__device__ inline void fma4(float4& a, const float4& v, float s) {
  a.x = fmaf(v.x, s, a.x);
  a.y = fmaf(v.y, s, a.y);
  a.z = fmaf(v.z, s, a.z);
  a.w = fmaf(v.w, s, a.w);
}

// ---------------- Stage 1: W-DFT  x(b,h,w,c) -> Xr,Xi(b,h,w',c), w' in [0,46) ---
// grid: (B*H, 4 w'-quarters of 12, 3 c-chunks of 256), block: 64
__global__ __launch_bounds__(64) void s1_wdft(const float* __restrict__ x,
                                              float* __restrict__ Xr,
                                              float* __restrict__ Xi) {
  const int bh   = blockIdx.x;
  const int qd   = blockIdx.y;
  const int cz   = blockIdx.z;
  const int lane = threadIdx.x;
  const int c0   = cz * 256 + lane * 4;

  __shared__ float ct[kW][12];
  __shared__ float st[kW][12];
  for (int idx = lane; idx < kW * 12; idx += 64) {
    const int w = idx / 12, q = idx % 12;
    const int wp = qd * 12 + q;
    float cv = 0.f, sv = 0.f;
    if (wp < kM) {
      const int r = (w * wp) % kW;
      const float ang = kTwoPi * (float)r / (float)kW;
      cv = cosf(ang) * kInv180;
      sv = -sinf(ang) * kInv180;   // Xi = -sum x*sin
    }
    ct[w][q] = cv;
    st[w][q] = sv;
  }
  __syncthreads();

  float4 ar[12], ai[12];
#pragma unroll
  for (int q = 0; q < 12; ++q) {
    ar[q] = make_float4(0.f, 0.f, 0.f, 0.f);
    ai[q] = make_float4(0.f, 0.f, 0.f, 0.f);
  }

  const float* xp = x + (size_t)bh * kW * kC + c0;
  for (int w = 0; w < kW; ++w) {
    const float4 xv = *(const float4*)(xp + (size_t)w * kC);
#pragma unroll
    for (int q = 0; q < 12; ++q) {
      fma4(ar[q], xv, ct[w][q]);
      fma4(ai[q], xv, st[w][q]);
    }
  }

#pragma unroll
  for (int q = 0; q < 12; ++q) {
    const int wp = qd * 12 + q;
    if (wp < kM) {
      const size_t o = ((size_t)bh * kM + wp) * kC + c0;
      *(float4*)(Xr + o) = ar[q];
      *(float4*)(Xi + o) = ai[q];
    }
  }
}

// ---------------- Stage 2/4: H-DFT (forward) / inverse H-DFT ------------------
// grid: (B*M, 12 h'-tiles of 8, 3 c-chunks), block: 64
template <bool INV>
__global__ __launch_bounds__(64) void s24_hdft(const float* __restrict__ Pr,
                                               const float* __restrict__ Pi,
                                               float* __restrict__ Qr,
                                               float* __restrict__ Qi) {
  const int bw   = blockIdx.x;
  const int ht   = blockIdx.y;
  const int cz   = blockIdx.z;
  const int lane = threadIdx.x;
  const int b  = bw / kM;
  const int wp = bw % kM;
  const int c0 = cz * 256 + lane * 4;

  __shared__ float ct[kH][8];
  __shared__ float st[kH][8];
  for (int idx = lane; idx < kH * 8; idx += 64) {
    const int h = idx / 8, q = idx % 8;
    const int hp = ht * 8 + q;
    float cv = 0.f, sv = 0.f;
    if (hp < kH) {
      const int r = (h * hp) % kH;
      const float ang = kTwoPi * (float)r / (float)kH;
      cv = cosf(ang) * kInv90;
      sv = sinf(ang) * kInv90;
    }
    ct[h][q] = cv;
    st[h][q] = sv;
  }
  __syncthreads();

  float4 ar[8], ai[8];
#pragma unroll
  for (int q = 0; q < 8; ++q) {
    ar[q] = make_float4(0.f, 0.f, 0.f, 0.f);
    ai[q] = make_float4(0.f, 0.f, 0.f, 0.f);
  }

  const size_t strideH = (size_t)kM * kC;
  const float* pr = Pr + (size_t)b * kH * strideH + (size_t)wp * kC + c0;
  const float* pi = Pi + (size_t)b * kH * strideH + (size_t)wp * kC + c0;

  for (int h = 0; h < kH; ++h) {
    const float4 xr = *(const float4*)(pr + (size_t)h * strideH);
    const float4 xi = *(const float4*)(pi + (size_t)h * strideH);
#pragma unroll
    for (int q = 0; q < 8; ++q) {
      const float cv = ct[h][q];
      const float sv = st[h][q];
      if (INV) {
        // Y = sum Z * e^{+i th}: Yr = Zr*c - Zi*s ; Yi = Zi*c + Zr*s
        fma4(ar[q], xr, cv); fma4(ar[q], xi, -sv);
        fma4(ai[q], xi, cv); fma4(ai[q], xr, sv);
      } else {
        // Y = sum X * e^{-i th}: Yr = Xr*c + Xi*s ; Yi = Xi*c - Xr*s
        fma4(ar[q], xr, cv); fma4(ar[q], xi, sv);
        fma4(ai[q], xi, cv); fma4(ai[q], xr, -sv);
      }
    }
  }

#pragma unroll
  for (int q = 0; q < 8; ++q) {
    const int hp = ht * 8 + q;
    if (hp < kH) {
      const size_t o = (((size_t)b * kH + hp) * kM + wp) * kC + c0;
      *(float4*)(Qr + o) = ar[q];
      *(float4*)(Qi + o) = ai[q];
    }
  }
}

// ---------------- Stage 3: block-diagonal complex MLP layer -------------------
// MODE 0: relu; MODE 1: softshrink. grid: (4140 position-tiles of 4, 3 c-chunks)
__device__ inline float activ(float v, int mode) {
  if (mode == 0) return v > 0.f ? v : 0.f;
  const float t = fabsf(v) - kLam;
  return t > 0.f ? copysignf(t, v) : 0.f;
}

template <int MODE>
__global__ __launch_bounds__(64) void s3_mlp(const float* __restrict__ inr,
                                             const float* __restrict__ ini,
                                             const float* __restrict__ wt,
                                             const float* __restrict__ bias,
                                             float* __restrict__ outr,
                                             float* __restrict__ outi) {
  const int pt   = blockIdx.x;
  const int cz   = blockIdx.y;
  const int lane = threadIdx.x;
  const int cc = cz * 256 + lane * 4;  // output channel (quad start)
  const int n  = cc / kBS;
  const int j  = cc % kBS;
  const int p0 = pt * 4;

  const float* w0p = wt + (size_t)n * kBS * kBS + j;            // wt[0][n][i][j]
  const float* w1p = wt + (size_t)(kNB + n) * kBS * kBS + j;    // wt[1][n][i][j]
  const float* rp = inr + (size_t)p0 * kC + n * kBS;
  const float* ip = ini + (size_t)p0 * kC + n * kBS;

  float4 ar[4], ai[4];
#pragma unroll
  for (int p = 0; p < 4; ++p) {
    ar[p] = make_float4(0.f, 0.f, 0.f, 0.f);
    ai[p] = make_float4(0.f, 0.f, 0.f, 0.f);
  }

  for (int i = 0; i < kBS; ++i) {
    const float4 a = *(const float4*)(w0p + (size_t)i * kBS);
    const float4 b = *(const float4*)(w1p + (size_t)i * kBS);
#pragma unroll
    for (int p = 0; p < 4; ++p) {
      const float xr = rp[(size_t)p * kC + i];
      const float xi = ip[(size_t)p * kC + i];
      // or = sum xr*w0 - xi*w1 ; oi = sum xi*w0 + xr*w1
      fma4(ar[p], a, xr); fma4(ar[p], b, -xi);
      fma4(ai[p], a, xi); fma4(ai[p], b, xr);
    }
  }

  const float4 br = *(const float4*)(bias + (size_t)n * kBS + j);
  const float4 bi = *(const float4*)(bias + (size_t)(kNB + n) * kBS + j);
#pragma unroll
  for (int p = 0; p < 4; ++p) {
    float4 vr = ar[p], vi = ai[p];
    vr.x = activ(vr.x + br.x, MODE); vr.y = activ(vr.y + br.y, MODE);
    vr.z = activ(vr.z + br.z, MODE); vr.w = activ(vr.w + br.w, MODE);
    vi.x = activ(vi.x + bi.x, MODE); vi.y = activ(vi.y + bi.y, MODE);
    vi.z = activ(vi.z + bi.z, MODE); vi.w = activ(vi.w + bi.w, MODE);
    const size_t o = (size_t)(p0 + p) * kC + cc;
    *(float4*)(outr + o) = vr;
    *(float4*)(outi + o) = vi;
  }
}

// ---------------- Stage 5: inverse W (46 complex -> 180 real) + residual ------
// grid: (B*H, 15 w-tiles of 12, 3 c-chunks), block: 64
__global__ __launch_bounds__(64) void s5_iwdft(const float* __restrict__ Ur,
                                               const float* __restrict__ Ui,
                                               const float* __restrict__ x,
                                               float* __restrict__ out) {
  const int bh   = blockIdx.x;
  const int wt   = blockIdx.y;
  const int cz   = blockIdx.z;
  const int lane = threadIdx.x;
  const int c0   = cz * 256 + lane * 4;

  __shared__ float ct[kM][12];
  __shared__ float st[kM][12];
  for (int idx = lane; idx < kM * 12; idx += 64) {
    const int wp = idx / 12, q = idx % 12;
    const int w = wt * 12 + q;
    float cv, sv;
    if (wp == 0) {
      cv = kInv180;  // DC: imag part dropped (pocketfft c2r), weight 1
      sv = 0.f;
    } else {
      const int r = (w * wp) % kW;
      const float ang = kTwoPi * (float)r / (float)kW;
      cv = 2.f * cosf(ang) * kInv180;   // Hermitian mirror: factor 2
      sv = -2.f * sinf(ang) * kInv180;
    }
    ct[wp][q] = cv;
    st[wp][q] = sv;
  }
  __syncthreads();

  float4 acc[12];
#pragma unroll
  for (int q = 0; q < 12; ++q) acc[q] = make_float4(0.f, 0.f, 0.f, 0.f);

  const float* pr = Ur + (size_t)bh * kM * kC + c0;
  const float* pi = Ui + (size_t)bh * kM * kC + c0;
  for (int wp = 0; wp < kM; ++wp) {
    const float4 zr = *(const float4*)(pr + (size_t)wp * kC);
    const float4 zi = *(const float4*)(pi + (size_t)wp * kC);
#pragma unroll
    for (int q = 0; q < 12; ++q) {
      fma4(acc[q], zr, ct[wp][q]);
      fma4(acc[q], zi, st[wp][q]);
    }
  }

#pragma unroll
  for (int q = 0; q < 12; ++q) {
    const int w = wt * 12 + q;
    const size_t o = ((size_t)bh * kW + w) * kC + c0;
    const float4 xv = *(const float4*)(x + o);
    float4 v = acc[q];
    v.x += xv.x; v.y += xv.y; v.z += xv.z; v.w += xv.w;
    *(float4*)(out + o) = v;
  }
}

}  // namespace

extern "C" void kernel_launch(void* const* d_in, const int* in_sizes, int n_in,
                              void* d_out, int out_size, void* d_ws, size_t ws_size,
                              hipStream_t stream) {
  const float* x  = (const float*)d_in[0];
  const float* w1 = (const float*)d_in[1];
  const float* b1 = (const float*)d_in[2];
  const float* w2 = (const float*)d_in[3];
  const float* b2 = (const float*)d_in[4];
  float* out = (float*)d_out;

  const size_t S = (size_t)kB * kH * kM * kC;  // 12,718,080 floats per buffer
  float* buf0 = (float*)d_ws;
  float* buf1 = buf0 + S;
  float* buf2 = buf1 + S;
  float* buf3 = buf2 + S;

  const dim3 blk(64);

  // 1) W-DFT: x -> (buf0, buf1) = Xr, Xi
  s1_wdft<<<dim3(kB * kH, 4, 3), blk, 0, stream>>>(x, buf0, buf1);
  // 2) H-DFT: -> (buf2, buf3)
  s24_hdft<false><<<dim3(kB * kM, 12, 3), blk, 0, stream>>>(buf0, buf1, buf2, buf3);
  // 3) MLP layer 1 (relu): -> (buf0, buf1)
  s3_mlp<0><<<dim3(4140, 3), blk, 0, stream>>>(buf2, buf3, w1, b1, buf0, buf1);
  //    MLP layer 2 (softshrink): -> (buf2, buf3)
  s3_mlp<1><<<dim3(4140, 3), blk, 0, stream>>>(buf0, buf1, w2, b2, buf2, buf3);
  // 4) inverse H-DFT: -> (buf0, buf1)
  s24_hdft<true><<<dim3(kB * kM, 12, 3), blk, 0, stream>>>(buf2, buf3, buf0, buf1);
  // 5) inverse W + residual: -> out
  s5_iwdft<<<dim3(kB * kH, 15, 3), blk, 0, stream>>>(buf0, buf1, x, out);
}

// Round 2
// 766.719 us; speedup vs baseline: 1.8097x; 1.8097x over previous
//
#include <hip/hip_runtime.h>
#include <math.h>

typedef __attribute__((ext_vector_type(8))) short short8;
typedef __attribute__((ext_vector_type(4))) float f32x4;

#define MFMA16 __builtin_amdgcn_mfma_f32_16x16x32_bf16

namespace {

constexpr float kI180 = 0.07453559924999299f;  // 1/sqrt(180)
constexpr float kI90  = 0.10540925533894598f;  // 1/sqrt(90)
constexpr float kTwoPi = 6.283185307179586f;

__device__ inline unsigned short f2b(float f) {
  unsigned u = __builtin_bit_cast(unsigned, f);
  u += 0x7fffu + ((u >> 16) & 1u);
  return (unsigned short)(u >> 16);
}
__device__ inline unsigned pack2(float a, float b) {
  return (unsigned)f2b(a) | ((unsigned)f2b(b) << 16);
}

// ---------------------------------------------------------------- prep ------
// Builds all bf16 constant matrices (B-operands, layout Bt[n][k], k contiguous)
// with zero padding embedded, plus fp32 biases.
__global__ void prep_k(short* cTw, short* cThf, short* cThi, short* cW1,
                       short* cW2, short* cTwi, float* fB1, float* fB2,
                       const float* __restrict__ w1, const float* __restrict__ b1,
                       const float* __restrict__ w2, const float* __restrict__ b2) {
  int gid = blockIdx.x * blockDim.x + threadIdx.x;
  int gs = gridDim.x * blockDim.x;
  // cTw[96][192]: n=(ri,w') (48+48), k=w. forward W-DFT.
  for (int i = gid; i < 96 * 192; i += gs) {
    int n = i / 192, k = i % 192;
    int ri = n / 48, wp = n % 48;
    float v = 0.f;
    if (wp < 46 && k < 180) {
      int r = (k * wp) % 180;
      float s, c;
      sincosf(kTwoPi * (float)r / 180.f, &s, &c);
      v = (ri == 0) ? c * kI180 : -s * kI180;
    }
    cTw[i] = (short)f2b(v);
  }
  // cThf[192][192]: n=(rj,h'), k=(ri,h). forward H-DFT.
  // cThi[192][192]: n=(rj,h),  k=(ri,h'). inverse H-DFT.
  for (int i = gid; i < 192 * 192; i += gs) {
    int n = i / 192, k = i % 192;
    int rj = n / 96, hp = n % 96;
    int ri = k / 96, h = k % 96;
    float vf = 0.f, vi = 0.f;
    if (hp < 90 && h < 90) {
      int r = (h * hp) % 90;
      float s, c;
      sincosf(kTwoPi * (float)r / 90.f, &s, &c);
      c *= kI90; s *= kI90;
      vf = (rj == 0) ? ((ri == 0) ? c : s) : ((ri == 0) ? -s : c);
      vi = (rj == 0) ? ((ri == 0) ? c : -s) : ((ri == 0) ? s : c);
    }
    cThf[i] = (short)f2b(vf);
    cThi[i] = (short)f2b(vi);
  }
  // cW1/cW2 [8][192][192]: per block n: Bt[j=(rj,o)][k=(ri,ci)]
  for (int i = gid; i < 8 * 192 * 192; i += gs) {
    int n = i / 36864, r2 = i % 36864;
    int j = r2 / 192, k = r2 % 192;
    int rj = j / 96, o = j % 96;
    int ri = k / 96, ci = k % 96;
    {
      float W0 = w1[((size_t)(n * 96 + ci)) * 96 + o];
      float W1v = w1[((size_t)((8 + n) * 96 + ci)) * 96 + o];
      float v = (rj == 0) ? ((ri == 0) ? W0 : -W1v) : ((ri == 0) ? W1v : W0);
      cW1[i] = (short)f2b(v);
    }
    {
      float W0 = w2[((size_t)(n * 96 + ci)) * 96 + o];
      float W1v = w2[((size_t)((8 + n) * 96 + ci)) * 96 + o];
      float v = (rj == 0) ? ((ri == 0) ? W0 : -W1v) : ((ri == 0) ? W1v : W0);
      cW2[i] = (short)f2b(v);
    }
  }
  // cTwi[192][96]: n=w, k=(ri,w'). inverse W (real output, Hermitian fold).
  for (int i = gid; i < 192 * 96; i += gs) {
    int n = i / 96, k = i % 96;
    int ri = k / 48, wp = k % 48;
    float v = 0.f;
    if (n < 180 && wp < 46) {
      int r = (n * wp) % 180;
      float s, c;
      sincosf(kTwoPi * (float)r / 180.f, &s, &c);
      if (ri == 0) v = ((wp == 0) ? 1.f : 2.f) * c * kI180;
      else v = (wp == 0) ? 0.f : -2.f * s * kI180;
    }
    cTwi[i] = (short)f2b(v);
  }
  // biases fp32: fB[n][j=(rj,o)]
  for (int i = gid; i < 8 * 192; i += gs) {
    int n = i / 192, j = i % 192;
    int rj = j / 96, o = j % 96;
    fB1[i] = b1[(size_t)(rj * 8 + n) * 96 + o];
    fB2[i] = b2[(size_t)(rj * 8 + n) * 96 + o];
  }
}

// ---------------------------------------------------------------- S1 --------
// Per (b,h): C[c 64][n=(ri,w') 96] = A(xT staged)[64][192w] * Bt(cTw)[96][192].
// Transposed store -> X1a[b][h][ri*48+w'][c 768] bf16.
__global__ __launch_bounds__(256) void s1_k(const float* __restrict__ x,
                                            const short* __restrict__ cTw,
                                            short* __restrict__ X1a) {
  __shared__ short Bl[96 * 200];
  __shared__ short Al[64 * 200];
  int t = threadIdx.x;
  int bh = blockIdx.x;
  int c0 = blockIdx.y * 64;
  for (int q = t; q < 96 * 24; q += 256) {
    int r = q / 24, s = q % 24;
    *(short8*)&Bl[r * 200 + s * 8] = *(const short8*)&cTw[r * 192 + s * 8];
  }
  unsigned* Ad = (unsigned*)Al;
  const float* xb = x + (size_t)bh * 180 * 768 + c0;
  for (int q = t; q < 90 * 16; q += 256) {
    int cq = q % 16, wp = q / 16;
    int w0 = wp * 2;
    const float4 a0 = *(const float4*)(xb + (size_t)w0 * 768 + cq * 4);
    const float4 a1 = *(const float4*)(xb + (size_t)(w0 + 1) * 768 + cq * 4);
    int cb = cq * 4;
    Ad[(cb + 0) * 100 + wp] = pack2(a0.x, a1.x);
    Ad[(cb + 1) * 100 + wp] = pack2(a0.y, a1.y);
    Ad[(cb + 2) * 100 + wp] = pack2(a0.z, a1.z);
    Ad[(cb + 3) * 100 + wp] = pack2(a0.w, a1.w);
  }
  for (int q = t; q < 64 * 6; q += 256) {
    int c = q / 6, wp = 90 + q % 6;
    Ad[c * 100 + wp] = 0u;
  }
  __syncthreads();
  int lane = t & 63, wv = t >> 6, ln = lane & 15, qd = lane >> 4;
  f32x4 z = {0.f, 0.f, 0.f, 0.f};
  f32x4 acc[6];
#pragma unroll
  for (int i = 0; i < 6; ++i) acc[i] = z;
  int arow = (wv * 16 + ln) * 200;
  for (int kc = 0; kc < 6; ++kc) {
    int ko = kc * 32 + qd * 8;
    short8 av = *(const short8*)&Al[arow + ko];
#pragma unroll
    for (int nf = 0; nf < 6; ++nf) {
      short8 bv = *(const short8*)&Bl[(nf * 16 + ln) * 200 + ko];
      acc[nf] = MFMA16(av, bv, acc[nf], 0, 0, 0);
    }
  }
  short* dst = X1a + (size_t)bh * 96 * 768;
  int cbase = c0 + wv * 16 + qd * 4;
#pragma unroll
  for (int nf = 0; nf < 6; ++nf) {
    int n = nf * 16 + ln;
    short4 v;
    v.x = (short)f2b(acc[nf][0]);
    v.y = (short)f2b(acc[nf][1]);
    v.z = (short)f2b(acc[nf][2]);
    v.w = (short)f2b(acc[nf][3]);
    *(short4*)&dst[(size_t)n * 768 + cbase] = v;
  }
}

// ---------------------------------------------------------------- T1 --------
// X1a[b][h][ri*48+w'][c] -> X1b[b][(w'*768+c)][(ri*96+h) 192], zero h-pads.
__global__ __launch_bounds__(256) void t1_k(const short* __restrict__ X1a,
                                            short* __restrict__ X1b) {
  __shared__ short L[64 * 104];
  unsigned* Ld = (unsigned*)L;
  int t = threadIdx.x;
  int gx = blockIdx.x;
  int c0 = blockIdx.y * 64;
  int b = gx / 92, r = gx % 92;
  int ri = r / 46, wp = r % 46;
  const short* src = X1a + ((size_t)(b * 90) * 96 + ri * 48 + wp) * 768 + c0;
  for (int q = t; q < 45 * 8; q += 256) {
    int hp = q % 45, seg = q / 45;
    int h0 = hp * 2;
    short8 r0 = *(const short8*)&src[(size_t)h0 * 73728 + seg * 8];
    short8 r1 = *(const short8*)&src[(size_t)(h0 + 1) * 73728 + seg * 8];
#pragma unroll
    for (int i = 0; i < 8; ++i) {
      int c = seg * 8 + i;
      Ld[c * 52 + hp] = (unsigned)(unsigned short)r0[i] |
                        ((unsigned)(unsigned short)r1[i] << 16);
    }
  }
  for (int q = t; q < 64 * 3; q += 256) {
    int c = q / 3, hp = 45 + q % 3;
    Ld[c * 52 + hp] = 0u;
  }
  __syncthreads();
  short* dst = X1b + (size_t)b * 35328 * 192 + ((size_t)wp * 768 + c0) * 192 + ri * 96;
  for (int q = t; q < 64 * 12; q += 256) {
    int c = q / 12, seg = q % 12;
    short8 v = *(const short8*)&L[c * 104 + seg * 8];
    *(short8*)&dst[(size_t)c * 192 + seg * 8] = v;
  }
}

// ---------------------------------------------------------------- S2/S4 -----
// Per b: C[m=(w'c) 35328][n 192] = A(data)[m][192] * Bt[n][192]; transposed
// store -> dst[b][n][m]. nh splits n into halves of 96 (LDS budget).
__global__ __launch_bounds__(256) void s24_k(const short* __restrict__ Asrc,
                                             const short* __restrict__ Bsrc,
                                             short* __restrict__ dst) {
  __shared__ short Bl[96 * 200];
  __shared__ short Al[64 * 200];
  int t = threadIdx.x;
  int mt = blockIdx.x, nh = blockIdx.y, b = blockIdx.z;
  for (int q = t; q < 96 * 24; q += 256) {
    int r = q / 24, s = q % 24;
    *(short8*)&Bl[r * 200 + s * 8] =
        *(const short8*)&Bsrc[(size_t)(nh * 96 + r) * 192 + s * 8];
  }
  const short* Ab = Asrc + ((size_t)b * 35328 + (size_t)mt * 64) * 192;
  for (int q = t; q < 64 * 24; q += 256) {
    *(short8*)&Al[(q / 24) * 200 + (q % 24) * 8] = *(const short8*)&Ab[q * 8];
  }
  __syncthreads();
  int lane = t & 63, wv = t >> 6, ln = lane & 15, qd = lane >> 4;
  f32x4 z = {0.f, 0.f, 0.f, 0.f};
  f32x4 acc[6];
#pragma unroll
  for (int i = 0; i < 6; ++i) acc[i] = z;
  int arow = (wv * 16 + ln) * 200;
  for (int kc = 0; kc < 6; ++kc) {
    int ko = kc * 32 + qd * 8;
    short8 av = *(const short8*)&Al[arow + ko];
#pragma unroll
    for (int nf = 0; nf < 6; ++nf) {
      short8 bv = *(const short8*)&Bl[(nf * 16 + ln) * 200 + ko];
      acc[nf] = MFMA16(av, bv, acc[nf], 0, 0, 0);
    }
  }
  size_t m0 = (size_t)mt * 64 + wv * 16 + qd * 4;
  short* db = dst + (size_t)b * 192 * 35328;
#pragma unroll
  for (int nf = 0; nf < 6; ++nf) {
    int n = nh * 96 + nf * 16 + ln;
    short4 v;
    v.x = (short)f2b(acc[nf][0]);
    v.y = (short)f2b(acc[nf][1]);
    v.z = (short)f2b(acc[nf][2]);
    v.w = (short)f2b(acc[nf][3]);
    *(short4*)&db[(size_t)n * 35328 + m0] = v;
  }
}

// ---------------------------------------------------------------- S3a -------
// MLP layer 1: per (n, pos-tile): A gathered from X2, B=cW1[n], relu(.+b).
// Output O1[n][p][j 192] (pos-major) via LDS retile.
__global__ __launch_bounds__(256) void s3a_k(const short* __restrict__ X2,
                                             const short* __restrict__ cW1,
                                             const float* __restrict__ fB1,
                                             short* __restrict__ O1) {
  __shared__ short Bl[96 * 200];
  __shared__ short Al[64 * 200];
  int t = threadIdx.x;
  int mt = blockIdx.x;
  int n = blockIdx.y >> 1, nh = blockIdx.y & 1;
  for (int q = t; q < 96 * 24; q += 256) {
    int r = q / 24, s = q % 24;
    *(short8*)&Bl[r * 200 + s * 8] =
        *(const short8*)&cW1[(size_t)n * 36864 + (size_t)(nh * 96 + r) * 192 + s * 8];
  }
  for (int q = t; q < 64 * 24; q += 256) {
    int pr = q / 24, j = q % 24;
    int ri = j / 12, seg = j % 12;
    int p = mt * 64 + pr;
    if (p > 16559) p = 16559;
    int pb = p / 4140, rem = p % 4140;
    int hp = rem / 46, wp = rem % 46;
    *(short8*)&Al[pr * 200 + ri * 96 + seg * 8] =
        *(const short8*)&X2[((size_t)pb * 192 + ri * 96 + hp) * 35328 +
                            (size_t)wp * 768 + n * 96 + seg * 8];
  }
  __syncthreads();
  int lane = t & 63, wv = t >> 6, ln = lane & 15, qd = lane >> 4;
  f32x4 z = {0.f, 0.f, 0.f, 0.f};
  f32x4 acc[6];
#pragma unroll
  for (int i = 0; i < 6; ++i) acc[i] = z;
  int arow = (wv * 16 + ln) * 200;
  for (int kc = 0; kc < 6; ++kc) {
    int ko = kc * 32 + qd * 8;
    short8 av = *(const short8*)&Al[arow + ko];
#pragma unroll
    for (int nf = 0; nf < 6; ++nf) {
      short8 bv = *(const short8*)&Bl[(nf * 16 + ln) * 200 + ko];
      acc[nf] = MFMA16(av, bv, acc[nf], 0, 0, 0);
    }
  }
  __syncthreads();  // done reading Al; reuse as retile buffer [64][104]
#pragma unroll
  for (int nf = 0; nf < 6; ++nf) {
    float bias = fB1[n * 192 + nh * 96 + nf * 16 + ln];
#pragma unroll
    for (int r = 0; r < 4; ++r) {
      float v = acc[nf][r] + bias;
      v = v > 0.f ? v : 0.f;
      Al[(wv * 16 + qd * 4 + r) * 104 + nf * 16 + ln] = (short)f2b(v);
    }
  }
  __syncthreads();
  for (int q = t; q < 64 * 12; q += 256) {
    int pr = q / 12, seg = q % 12;
    int p = mt * 64 + pr;
    if (p < 16560) {
      *(short8*)&O1[((size_t)n * 16576 + p) * 192 + nh * 96 + seg * 8] =
          *(const short8*)&Al[pr * 104 + seg * 8];
    }
  }
}

// ---------------------------------------------------------------- S3b -------
// MLP layer 2: A = O1 rows (contiguous), B=cW2[n], softshrink(.+b).
// Transposed store -> O2[n][j 192][p] (chan-major).
__global__ __launch_bounds__(256) void s3b_k(const short* __restrict__ O1,
                                             const short* __restrict__ cW2,
                                             const float* __restrict__ fB2,
                                             short* __restrict__ O2) {
  __shared__ short Bl[96 * 200];
  __shared__ short Al[64 * 200];
  int t = threadIdx.x;
  int mt = blockIdx.x;
  int n = blockIdx.y >> 1, nh = blockIdx.y & 1;
  for (int q = t; q < 96 * 24; q += 256) {
    int r = q / 24, s = q % 24;
    *(short8*)&Bl[r * 200 + s * 8] =
        *(const short8*)&cW2[(size_t)n * 36864 + (size_t)(nh * 96 + r) * 192 + s * 8];
  }
  for (int q = t; q < 64 * 24; q += 256) {
    int pr = q / 24, seg = q % 24;
    int p = mt * 64 + pr;
    if (p > 16559) p = 16559;
    *(short8*)&Al[pr * 200 + seg * 8] =
        *(const short8*)&O1[((size_t)n * 16576 + p) * 192 + seg * 8];
  }
  __syncthreads();
  int lane = t & 63, wv = t >> 6, ln = lane & 15, qd = lane >> 4;
  f32x4 z = {0.f, 0.f, 0.f, 0.f};
  f32x4 acc[6];
#pragma unroll
  for (int i = 0; i < 6; ++i) acc[i] = z;
  int arow = (wv * 16 + ln) * 200;
  for (int kc = 0; kc < 6; ++kc) {
    int ko = kc * 32 + qd * 8;
    short8 av = *(const short8*)&Al[arow + ko];
#pragma unroll
    for (int nf = 0; nf < 6; ++nf) {
      short8 bv = *(const short8*)&Bl[(nf * 16 + ln) * 200 + ko];
      acc[nf] = MFMA16(av, bv, acc[nf], 0, 0, 0);
    }
  }
  size_t p0 = (size_t)mt * 64 + wv * 16 + qd * 4;
  if (p0 < 16560) {
#pragma unroll
    for (int nf = 0; nf < 6; ++nf) {
      int j = nh * 96 + nf * 16 + ln;
      float bias = fB2[n * 192 + j];
      short4 v;
      float s0;
      s0 = acc[nf][0] + bias; s0 = fabsf(s0) > 0.01f ? copysignf(fabsf(s0) - 0.01f, s0) : 0.f; v.x = (short)f2b(s0);
      s0 = acc[nf][1] + bias; s0 = fabsf(s0) > 0.01f ? copysignf(fabsf(s0) - 0.01f, s0) : 0.f; v.y = (short)f2b(s0);
      s0 = acc[nf][2] + bias; s0 = fabsf(s0) > 0.01f ? copysignf(fabsf(s0) - 0.01f, s0) : 0.f; v.z = (short)f2b(s0);
      s0 = acc[nf][3] + bias; s0 = fabsf(s0) > 0.01f ? copysignf(fabsf(s0) - 0.01f, s0) : 0.f; v.w = (short)f2b(s0);
      *(short4*)&O2[((size_t)n * 192 + j) * 16576 + p0] = v;
    }
  }
}

// ---------------------------------------------------------------- T2 --------
// O2[n][(rj,o)][pos] -> X3[b][(w'*768+n*96+o)][(rj*96+h')], zero h'-pads.
__global__ __launch_bounds__(256) void t2_k(const short* __restrict__ O2,
                                            short* __restrict__ X3) {
  __shared__ short L[16 * 1488];
  int t = threadIdx.x;
  int gx = blockIdx.x;
  int ht = gx % 3; gx /= 3;
  int ot = gx % 6; gx /= 6;
  int rj = gx % 2; gx /= 2;
  int n = gx % 8;
  int b = gx / 8;
  int h0 = ht * 32;
  int nh = min(32, 90 - h0);
  int o0 = ot * 16;
  int posbase = (b * 90 + h0) * 46;
  int pa = posbase & ~7;
  int d = posbase - pa;
  int vlen = d + 46 * nh;
  int segs = (vlen + 7) / 8;
  for (int q = t; q < 16 * 186; q += 256) {
    int orl = q / 186, seg = q % 186;
    if (seg < segs) {
      short8 v = *(const short8*)&O2[((size_t)n * 192 + rj * 96 + o0 + orl) * 16576 +
                                     pa + seg * 8];
      int base = seg * 8;
      if (base >= d && base + 8 <= vlen) {
        *(short8*)&L[orl * 1488 + base] = v;
      } else {
#pragma unroll
        for (int i = 0; i < 8; ++i) {
          int col = base + i;
          L[orl * 1488 + col] = (col >= d && col < vlen) ? v[i] : (short)0;
        }
      }
    } else {
      short8 zz = {0, 0, 0, 0, 0, 0, 0, 0};
      *(short8*)&L[orl * 1488 + seg * 8] = zz;
    }
  }
  __syncthreads();
  short* dst = X3 + (size_t)b * 35328 * 192;
  for (int q = t; q < 46 * 64; q += 256) {
    int wp = q >> 6;
    int rem = q & 63;
    int orl = rem >> 2, seg = rem & 3;
    short8 v;
#pragma unroll
    for (int i = 0; i < 8; ++i) {
      int hrel = seg * 8 + i;
      v[i] = L[orl * 1488 + d + hrel * 46 + wp];
    }
    *(short8*)&dst[((size_t)wp * 768 + n * 96 + o0 + orl) * 192 + rj * 96 + h0 +
                   seg * 8] = v;
  }
}

// ---------------------------------------------------------------- S5 --------
// Per (b,h): C[c 64][w 192] = A(X4 gathered)[64][96] * Bt(cTwi)[192][96];
// epilogue: + x residual, fp32 store.
__global__ __launch_bounds__(256) void s5_k(const short* __restrict__ X4,
                                            const short* __restrict__ cTwi,
                                            const float* __restrict__ x,
                                            float* __restrict__ out) {
  __shared__ short Bl[192 * 104];
  __shared__ short Al[64 * 104];
  int t = threadIdx.x;
  int bh = blockIdx.x;
  int c0 = blockIdx.y * 64;
  int b = bh / 90, h = bh % 90;
  for (int q = t; q < 192 * 12; q += 256) {
    int r = q / 12, s = q % 12;
    *(short8*)&Bl[r * 104 + s * 8] = *(const short8*)&cTwi[r * 96 + s * 8];
  }
  for (int q = t; q < 96 * 8; q += 256) {
    int k = q % 96, cs = q / 96;
    int ri = k / 48, wp = k % 48;
    if (wp > 45) wp = 45;
    short8 v = *(const short8*)&X4[((size_t)b * 192 + ri * 96 + h) * 35328 +
                                   (size_t)wp * 768 + c0 + cs * 8];
#pragma unroll
    for (int i = 0; i < 8; ++i) Al[(cs * 8 + i) * 104 + k] = v[i];
  }
  __syncthreads();
  int lane = t & 63, wv = t >> 6, ln = lane & 15, qd = lane >> 4;
  f32x4 z = {0.f, 0.f, 0.f, 0.f};
  f32x4 acc[12];
#pragma unroll
  for (int i = 0; i < 12; ++i) acc[i] = z;
  int arow = (wv * 16 + ln) * 104;
  for (int kc = 0; kc < 3; ++kc) {
    int ko = kc * 32 + qd * 8;
    short8 av = *(const short8*)&Al[arow + ko];
#pragma unroll
    for (int nf = 0; nf < 12; ++nf) {
      short8 bv = *(const short8*)&Bl[(nf * 16 + ln) * 104 + ko];
      acc[nf] = MFMA16(av, bv, acc[nf], 0, 0, 0);
    }
  }
  int cb = c0 + wv * 16 + qd * 4;
  const float* xr = x + (size_t)bh * 180 * 768;
  float* ob = out + (size_t)bh * 180 * 768;
#pragma unroll
  for (int nf = 0; nf < 12; ++nf) {
    int w = nf * 16 + ln;
    if (w < 180) {
      float4 xv = *(const float4*)&xr[(size_t)w * 768 + cb];
      float4 o;
      o.x = acc[nf][0] + xv.x;
      o.y = acc[nf][1] + xv.y;
      o.z = acc[nf][2] + xv.z;
      o.w = acc[nf][3] + xv.w;
      *(float4*)&ob[(size_t)w * 768 + cb] = o;
    }
  }
}

}  // namespace

extern "C" void kernel_launch(void* const* d_in, const int* in_sizes, int n_in,
                              void* d_out, int out_size, void* d_ws, size_t ws_size,
                              hipStream_t stream) {
  const float* x = (const float*)d_in[0];
  const float* w1 = (const float*)d_in[1];
  const float* b1 = (const float*)d_in[2];
  const float* w2 = (const float*)d_in[3];
  const float* b2 = (const float*)d_in[4];
  float* out = (float*)d_out;

  size_t off = 0;
  auto carve = [&](size_t bytes) -> char* {
    char* p = (char*)d_ws + off;
    off += (bytes + 255) & ~(size_t)255;
    return p;
  };
  short* cTw = (short*)carve(96 * 192 * 2);
  short* cThf = (short*)carve(192 * 192 * 2);
  short* cThi = (short*)carve(192 * 192 * 2);
  short* cW1 = (short*)carve(8 * 192 * 192 * 2);
  short* cW2 = (short*)carve(8 * 192 * 192 * 2);
  short* cTwi = (short*)carve(192 * 96 * 2);
  float* fB1 = (float*)carve(8 * 192 * 4);
  float* fB2 = (float*)carve(8 * 192 * 4);
  const size_t SLOT = 27131904;  // shorts (= 4*192*35328)
  short* slotA = (short*)carve(SLOT * 2);
  short* slotB = (short*)carve(SLOT * 2);
  // liveness-based aliasing:
  short* X1a = slotA;  // S1 -> T1
  short* X1b = slotB;  // T1 -> S2
  short* X2 = slotA;   // S2 -> S3a
  short* O1 = slotB;   // S3a -> S3b
  short* O2 = slotA;   // S3b -> T2
  short* X3 = slotB;   // T2 -> S4
  short* X4 = slotA;   // S4 -> S5

  prep_k<<<512, 256, 0, stream>>>(cTw, cThf, cThi, cW1, cW2, cTwi, fB1, fB2,
                                  w1, b1, w2, b2);
  s1_k<<<dim3(360, 12), 256, 0, stream>>>(x, cTw, X1a);
  t1_k<<<dim3(368, 12), 256, 0, stream>>>(X1a, X1b);
  s24_k<<<dim3(552, 2, 4), 256, 0, stream>>>(X1b, cThf, X2);
  s3a_k<<<dim3(259, 16), 256, 0, stream>>>(X2, cW1, fB1, O1);
  s3b_k<<<dim3(259, 16), 256, 0, stream>>>(O1, cW2, fB2, O2);
  t2_k<<<dim3(1152), 256, 0, stream>>>(O2, X3);
  s24_k<<<dim3(552, 2, 4), 256, 0, stream>>>(X3, cThi, X4);
  s5_k<<<dim3(360, 12), 256, 0, stream>>>(X4, cTwi, x, out);
}